// Round 1
// baseline (1800.248 us; speedup 1.0000x reference)
//
#include <hip/hip_runtime.h>

typedef unsigned short u16;
typedef unsigned int u32;
typedef __attribute__((ext_vector_type(8))) short short8;   // 8 x bf16 bits (4 VGPRs)
typedef __attribute__((ext_vector_type(8))) u16 ushort8;
typedef __attribute__((ext_vector_type(4))) float f32x4;

#define IN_DIM 4096
#define OUT_DIM 11008
#define MDIM 8192

// round-to-nearest-even fp32 -> bf16 bits (values are finite/well-behaved here)
__device__ __forceinline__ u16 f2bf(float f) {
  union { float f; u32 u; } v; v.f = f;
  const u32 u = v.u;
  return (u16)((u + 0x7FFFu + ((u >> 16) & 1u)) >> 16);
}

// ---------------------------------------------------------------------------
// Kernel 1: AWQ dequant. Each thread: 4 int32 -> 8 weights -> one 16B bf16 store.
// flat index f = o*IN + i ; group g = f/128 ; chunk of 8 never crosses a group.
// ---------------------------------------------------------------------------
__global__ void dequant_kernel(const int* __restrict__ packed,
                               const float* __restrict__ scales,
                               const float* __restrict__ offsets,
                               const float* __restrict__ inv_scale,
                               u16* __restrict__ W) {
  const int t = blockIdx.x * 256 + threadIdx.x;      // 0 .. 5,636,095
  const int4 p = ((const int4*)packed)[t];
  const int f0 = t * 8;                               // flat weight index (<45M, fits int)
  const int g = f0 >> 7;                              // group of 128
  const int i0 = f0 & (IN_DIM - 1);                   // input-channel index
  const float s = scales[g];
  const float o = offsets[g];
  const float4 iv0 = *(const float4*)(inv_scale + i0);
  const float4 iv1 = *(const float4*)(inv_scale + i0 + 4);

  const float w0 = fmaf((float)(p.x & 15),        s, o) * iv0.x;
  const float w1 = fmaf((float)((p.x >> 4) & 15), s, o) * iv0.y;
  const float w2 = fmaf((float)(p.y & 15),        s, o) * iv0.z;
  const float w3 = fmaf((float)((p.y >> 4) & 15), s, o) * iv0.w;
  const float w4 = fmaf((float)(p.z & 15),        s, o) * iv1.x;
  const float w5 = fmaf((float)((p.z >> 4) & 15), s, o) * iv1.y;
  const float w6 = fmaf((float)(p.w & 15),        s, o) * iv1.z;
  const float w7 = fmaf((float)((p.w >> 4) & 15), s, o) * iv1.w;

  ushort8 r;
  r[0] = f2bf(w0); r[1] = f2bf(w1); r[2] = f2bf(w2); r[3] = f2bf(w3);
  r[4] = f2bf(w4); r[5] = f2bf(w5); r[6] = f2bf(w6); r[7] = f2bf(w7);
  *(ushort8*)(W + f0) = r;
}

// ---------------------------------------------------------------------------
// Kernel 2: x fp32 -> bf16. Each thread: two float4 loads -> one 16B store.
// ---------------------------------------------------------------------------
__global__ void castx_kernel(const float* __restrict__ x, u16* __restrict__ xb) {
  const int t = blockIdx.x * 256 + threadIdx.x;       // 0 .. 4,194,303
  const float4 a = ((const float4*)x)[t * 2];
  const float4 b = ((const float4*)x)[t * 2 + 1];
  ushort8 r;
  r[0] = f2bf(a.x); r[1] = f2bf(a.y); r[2] = f2bf(a.z); r[3] = f2bf(a.w);
  r[4] = f2bf(b.x); r[5] = f2bf(b.y); r[6] = f2bf(b.z); r[7] = f2bf(b.w);
  *(ushort8*)(xb + t * 8) = r;
}

// ---------------------------------------------------------------------------
// Kernel 3: m97-style bf16 GEMM, C = A * B^T + bias.
// A [M,K] bf16 row-major, B [N,K] bf16 row-major (the dequantized weight),
// C [M,N] fp32. 128x128 block tile, BK=32, 4 waves (2x2), each wave 64x64
// via 4x4 grid of 16x16x32 MFMAs. Staging via global_load_lds width=16.
// ---------------------------------------------------------------------------
__device__ __forceinline__ void gload_lds16(const u16* g, u16* l) {
  using gvp = const __attribute__((address_space(1))) void*;
  using lvp = __attribute__((address_space(3))) void*;
  __builtin_amdgcn_global_load_lds((gvp)g, (lvp)l, 16, 0, 0);
}

__global__ void gemm_kernel(const u16* __restrict__ A,   // [MDIM, IN_DIM] bf16
                            const u16* __restrict__ B,   // [OUT_DIM, IN_DIM] bf16
                            const float* __restrict__ bias,
                            float* __restrict__ C) {
  constexpr int K = IN_DIM;
  constexpr int N = OUT_DIM;
  __shared__ u16 sA[128 * 32];   // 8 KB
  __shared__ u16 sB[128 * 32];   // 8 KB

  const int tid  = threadIdx.x;
  const int wave = tid >> 6;
  const int lane = tid & 63;
  const int m0 = blockIdx.y * 128;
  const int n0 = blockIdx.x * 128;
  const int wm = (wave >> 1) * 64;   // wave's m-offset in block tile
  const int wn = (wave & 1) * 64;    // wave's n-offset in block tile

  // --- staging addressing -------------------------------------------------
  // Tile is 128 rows x 32 cols bf16, row-major in LDS (8192 B).
  // global_load_lds: wave-uniform LDS base + lane*16; lane l of wave w covers
  // tile elements [w*512 + l*8 , +8) (chunk 0) and +2048 (chunk 1).
  const int srow = tid >> 2;          // 0..63
  const int scol = (tid & 3) * 8;
  const u16* gA0 = A + (size_t)(m0 + srow) * K + scol;
  const u16* gA1 = A + (size_t)(m0 + srow + 64) * K + scol;
  const u16* gB0 = B + (size_t)(n0 + srow) * K + scol;
  const u16* gB1 = B + (size_t)(n0 + srow + 64) * K + scol;
  u16* lA0 = sA + wave * 512;          // wave-uniform bases (bytes: wave*1024)
  u16* lA1 = sA + 2048 + wave * 512;
  u16* lB0 = sB + wave * 512;
  u16* lB1 = sB + 2048 + wave * 512;

  // --- fragment addressing ------------------------------------------------
  // A-frag: A[m = lane&15][k = (lane>>4)*8 + j]  -> one ds_read_b128 per tile.
  const int lr = lane >> 4;   // quad 0..3
  const int lc = lane & 15;
  const u16* fa = sA + (wm + lc) * 32 + lr * 8;   // +mi*512 per 16-row tile
  const u16* fb = sB + (wn + lc) * 32 + lr * 8;

  f32x4 acc[4][4] = {};

  for (int k = 0; k < K; k += 32) {
    gload_lds16(gA0, lA0);
    gload_lds16(gA1, lA1);
    gload_lds16(gB0, lB0);
    gload_lds16(gB1, lB1);
    gA0 += 32; gA1 += 32; gB0 += 32; gB1 += 32;
    __syncthreads();   // drains vmcnt -> staged data visible

    short8 af[4], bf[4];
#pragma unroll
    for (int i = 0; i < 4; ++i) af[i] = *(const short8*)(fa + i * 512);
#pragma unroll
    for (int i = 0; i < 4; ++i) bf[i] = *(const short8*)(fb + i * 512);
#pragma unroll
    for (int mi = 0; mi < 4; ++mi)
#pragma unroll
      for (int ni = 0; ni < 4; ++ni)
        acc[mi][ni] = __builtin_amdgcn_mfma_f32_16x16x32_bf16(
            af[mi], bf[ni], acc[mi][ni], 0, 0, 0);

    __syncthreads();   // all waves done reading before next overwrite
  }

  // --- epilogue: C/D layout col = lane&15, row = (lane>>4)*4 + reg ---------
  const int cm = m0 + wm + lr * 4;
  const int cn = n0 + wn + lc;
#pragma unroll
  for (int ni = 0; ni < 4; ++ni) {
    const int n = cn + ni * 16;
    const float bv = bias[n];
#pragma unroll
    for (int mi = 0; mi < 4; ++mi) {
      const int m = cm + mi * 16;
      float* cp = C + (size_t)m * N + n;
      cp[0]             = acc[mi][ni][0] + bv;
      cp[(size_t)N]     = acc[mi][ni][1] + bv;
      cp[(size_t)2 * N] = acc[mi][ni][2] + bv;
      cp[(size_t)3 * N] = acc[mi][ni][3] + bv;
    }
  }
}

// ---------------------------------------------------------------------------
extern "C" void kernel_launch(void* const* d_in, const int* in_sizes, int n_in,
                              void* d_out, int out_size, void* d_ws, size_t ws_size,
                              hipStream_t stream) {
  const float* x         = (const float*)d_in[0];
  const int*   packed    = (const int*)d_in[1];
  const float* scales    = (const float*)d_in[2];
  const float* offsets   = (const float*)d_in[3];
  const float* inv_scale = (const float*)d_in[4];
  const float* bias      = (const float*)d_in[5];
  float* out = (float*)d_out;

  // workspace layout: W bf16 [OUT,IN] (90.2 MB) | xb bf16 [M,IN] (67.1 MB)
  u16* W  = (u16*)d_ws;
  u16* xb = W + (size_t)OUT_DIM * IN_DIM;

  dequant_kernel<<<dim3((OUT_DIM * IN_DIM / 8) / 256), dim3(256), 0, stream>>>(
      packed, scales, offsets, inv_scale, W);
  castx_kernel<<<dim3((MDIM * IN_DIM / 8) / 256), dim3(256), 0, stream>>>(x, xb);
  gemm_kernel<<<dim3(OUT_DIM / 128, MDIM / 128), dim3(256), 0, stream>>>(
      xb, W, bias, out);
}

// Round 2
// 1344.966 us; speedup vs baseline: 1.3385x; 1.3385x over previous
//
#include <hip/hip_runtime.h>

typedef unsigned short u16;
typedef unsigned int u32;
typedef __attribute__((ext_vector_type(8))) short short8;   // 8 x bf16 bits (4 VGPRs)
typedef __attribute__((ext_vector_type(8))) u16 ushort8;
typedef __attribute__((ext_vector_type(4))) float f32x4;

#define IN_DIM 4096
#define OUT_DIM 11008
#define MDIM 8192

// round-to-nearest-even fp32 -> bf16 bits
__device__ __forceinline__ u16 f2bf(float f) {
  union { float f; u32 u; } v; v.f = f;
  const u32 u = v.u;
  return (u16)((u + 0x7FFFu + ((u >> 16) & 1u)) >> 16);
}

// ---------------------------------------------------------------------------
// Kernel 1: AWQ dequant. 4 int32 -> 8 weights -> one 16B bf16 store per thread.
// ---------------------------------------------------------------------------
__global__ void dequant_kernel(const int* __restrict__ packed,
                               const float* __restrict__ scales,
                               const float* __restrict__ offsets,
                               const float* __restrict__ inv_scale,
                               u16* __restrict__ W) {
  const int t = blockIdx.x * 256 + threadIdx.x;
  const int4 p = ((const int4*)packed)[t];
  const int f0 = t * 8;
  const int g = f0 >> 7;
  const int i0 = f0 & (IN_DIM - 1);
  const float s = scales[g];
  const float o = offsets[g];
  const float4 iv0 = *(const float4*)(inv_scale + i0);
  const float4 iv1 = *(const float4*)(inv_scale + i0 + 4);

  const float w0 = fmaf((float)(p.x & 15),        s, o) * iv0.x;
  const float w1 = fmaf((float)((p.x >> 4) & 15), s, o) * iv0.y;
  const float w2 = fmaf((float)(p.y & 15),        s, o) * iv0.z;
  const float w3 = fmaf((float)((p.y >> 4) & 15), s, o) * iv0.w;
  const float w4 = fmaf((float)(p.z & 15),        s, o) * iv1.x;
  const float w5 = fmaf((float)((p.z >> 4) & 15), s, o) * iv1.y;
  const float w6 = fmaf((float)(p.w & 15),        s, o) * iv1.z;
  const float w7 = fmaf((float)((p.w >> 4) & 15), s, o) * iv1.w;

  ushort8 r;
  r[0] = f2bf(w0); r[1] = f2bf(w1); r[2] = f2bf(w2); r[3] = f2bf(w3);
  r[4] = f2bf(w4); r[5] = f2bf(w5); r[6] = f2bf(w6); r[7] = f2bf(w7);
  *(ushort8*)(W + f0) = r;
}

// ---------------------------------------------------------------------------
// Kernel 2: x fp32 -> bf16.
// ---------------------------------------------------------------------------
__global__ void castx_kernel(const float* __restrict__ x, u16* __restrict__ xb) {
  const int t = blockIdx.x * 256 + threadIdx.x;
  const float4 a = ((const float4*)x)[t * 2];
  const float4 b = ((const float4*)x)[t * 2 + 1];
  ushort8 r;
  r[0] = f2bf(a.x); r[1] = f2bf(a.y); r[2] = f2bf(a.z); r[3] = f2bf(a.w);
  r[4] = f2bf(b.x); r[5] = f2bf(b.y); r[6] = f2bf(b.z); r[7] = f2bf(b.w);
  *(ushort8*)(xb + t * 8) = r;
}

// ---------------------------------------------------------------------------
// Kernel 3: bf16 GEMM, C = A * B^T + bias.  128x128 tile, BK=32, 4 waves.
// Grid: 1D, locality-swizzled into n-supertiles of GROUP_N n-blocks x all
// m-blocks (n fastest) so B panel + A stay LLC-resident.
// LDS layout XOR-swizzled: 16B chunk c stored at c ^ (row & 3).
// ---------------------------------------------------------------------------
__device__ __forceinline__ void gload_lds16(const u16* g, u16* l) {
  using gvp = const __attribute__((address_space(1))) void*;
  using lvp = __attribute__((address_space(3))) void*;
  __builtin_amdgcn_global_load_lds((gvp)g, (lvp)l, 16, 0, 0);
}

#define NB_N (OUT_DIM / 128)   // 86
#define NB_M (MDIM / 128)      // 64
#define GROUP_N 16             // n-blocks per supertile; NB_M*GROUP_N = 1024

__global__ void gemm_kernel(const u16* __restrict__ A,   // [MDIM, IN_DIM] bf16
                            const u16* __restrict__ B,   // [OUT_DIM, IN_DIM] bf16
                            const float* __restrict__ bias,
                            float* __restrict__ C) {
  constexpr int K = IN_DIM;
  constexpr int N = OUT_DIM;
  __shared__ u16 sA[128 * 32];   // 8 KB
  __shared__ u16 sB[128 * 32];   // 8 KB

  const int tid  = threadIdx.x;
  const int wave = tid >> 6;
  const int lane = tid & 63;

  // --- locality swizzle ---------------------------------------------------
  const int bid   = blockIdx.x;
  const int group = bid >> 10;          // / (NB_M * GROUP_N)
  const int rem   = bid & 1023;
  const int gn    = group * GROUP_N;
  const int gwid  = (NB_N - gn) < GROUP_N ? (NB_N - gn) : GROUP_N;
  const int nb    = gn + rem % gwid;    // n fastest: A tile reused by gwid
  const int mb    = rem / gwid;         //           consecutive blocks
  const int m0 = mb * 128;
  const int n0 = nb * 128;

  const int wm = (wave >> 1) * 64;
  const int wn = (wave & 1) * 64;

  // --- staging addressing (XOR-swizzled column) ---------------------------
  // LDS 16B-chunk slot s = region*256 + tid; row r = s>>2 (mod 128 rows),
  // stored chunk c_lds = s&3 holds logical chunk c = (s&3) ^ (r&3).
  const int srow = tid >> 2;                                    // 0..63
  const int scol = (((tid & 3) ^ ((tid >> 2) & 3))) * 8;        // swizzled
  const u16* gA0 = A + (size_t)(m0 + srow) * K + scol;
  const u16* gA1 = A + (size_t)(m0 + srow + 64) * K + scol;
  const u16* gB0 = B + (size_t)(n0 + srow) * K + scol;
  const u16* gB1 = B + (size_t)(n0 + srow + 64) * K + scol;
  u16* lA0 = sA + wave * 512;
  u16* lA1 = sA + 2048 + wave * 512;
  u16* lB0 = sB + wave * 512;
  u16* lB1 = sB + 2048 + wave * 512;

  // --- fragment addressing (read through the same swizzle) ----------------
  const int lr = lane >> 4;   // quad 0..3 = logical k-chunk
  const int lc = lane & 15;
  const u16* fa = sA + (wm + lc) * 32 + (lr ^ (lc & 3)) * 8;
  const u16* fb = sB + (wn + lc) * 32 + (lr ^ (lc & 3)) * 8;

  f32x4 acc[4][4] = {};

  for (int k = 0; k < K; k += 32) {
    gload_lds16(gA0, lA0);
    gload_lds16(gA1, lA1);
    gload_lds16(gB0, lB0);
    gload_lds16(gB1, lB1);
    gA0 += 32; gA1 += 32; gB0 += 32; gB1 += 32;
    __syncthreads();

    short8 af[4], bf[4];
#pragma unroll
    for (int i = 0; i < 4; ++i) af[i] = *(const short8*)(fa + i * 512);
#pragma unroll
    for (int i = 0; i < 4; ++i) bf[i] = *(const short8*)(fb + i * 512);
#pragma unroll
    for (int mi = 0; mi < 4; ++mi)
#pragma unroll
      for (int ni = 0; ni < 4; ++ni)
        acc[mi][ni] = __builtin_amdgcn_mfma_f32_16x16x32_bf16(
            af[mi], bf[ni], acc[mi][ni], 0, 0, 0);

    __syncthreads();
  }

  // --- epilogue: C/D layout col = lane&15, row = (lane>>4)*4 + reg ---------
  const int cm = m0 + wm + lr * 4;
  const int cn = n0 + wn + lc;
#pragma unroll
  for (int ni = 0; ni < 4; ++ni) {
    const int n = cn + ni * 16;
    const float bv = bias[n];
#pragma unroll
    for (int mi = 0; mi < 4; ++mi) {
      const int m = cm + mi * 16;
      float* cp = C + (size_t)m * N + n;
      cp[0]             = acc[mi][ni][0] + bv;
      cp[(size_t)N]     = acc[mi][ni][1] + bv;
      cp[(size_t)2 * N] = acc[mi][ni][2] + bv;
      cp[(size_t)3 * N] = acc[mi][ni][3] + bv;
    }
  }
}

// ---------------------------------------------------------------------------
extern "C" void kernel_launch(void* const* d_in, const int* in_sizes, int n_in,
                              void* d_out, int out_size, void* d_ws, size_t ws_size,
                              hipStream_t stream) {
  const float* x         = (const float*)d_in[0];
  const int*   packed    = (const int*)d_in[1];
  const float* scales    = (const float*)d_in[2];
  const float* offsets   = (const float*)d_in[3];
  const float* inv_scale = (const float*)d_in[4];
  const float* bias      = (const float*)d_in[5];
  float* out = (float*)d_out;

  u16* W  = (u16*)d_ws;                          // bf16 [OUT, IN]
  u16* xb = W + (size_t)OUT_DIM * IN_DIM;        // bf16 [M, IN]

  dequant_kernel<<<dim3((OUT_DIM * IN_DIM / 8) / 256), dim3(256), 0, stream>>>(
      packed, scales, offsets, inv_scale, W);
  castx_kernel<<<dim3((MDIM * IN_DIM / 8) / 256), dim3(256), 0, stream>>>(x, xb);
  gemm_kernel<<<dim3(NB_N * NB_M), dim3(256), 0, stream>>>(xb, W, bias, out);
}